// Round 5
// baseline (346.618 us; speedup 1.0000x reference)
//
#include <hip/hip_runtime.h>

#define DIN 128
#define DOUT 64
#define NEG_SLOPE 0.2f
#define ALPHA 0.5f

__device__ __forceinline__ float lrelu(float x) { return x > 0.0f ? x : NEG_SLOPE * x; }

__device__ __forceinline__ unsigned short f2bf(float f) {
    unsigned u = __float_as_uint(f);
    unsigned r = (u + 0x7fffu + ((u >> 16) & 1u)) >> 16;
    return (unsigned short)r;
}
__device__ __forceinline__ float bf2f(unsigned short h) {
    return __uint_as_float((unsigned)h << 16);
}
__device__ __forceinline__ float readlane_f(float v, int l) {
    return __int_as_float(__builtin_amdgcn_readlane(__float_as_int(v), l));
}

// ---------------- proj: xw = x@W (bf16 out) + 4 per-node score dots (f32).
// Block = 256 thr (4 waves). W1+W2 in LDS (64 KB), x tile (16 rows) in LDS.
__global__ __launch_bounds__(256) void proj_kernel(
    const float* __restrict__ x,
    const float* __restrict__ W1, const float* __restrict__ W2,
    const float* __restrict__ as1, const float* __restrict__ ad1,
    const float* __restrict__ as2, const float* __restrict__ ad2,
    unsigned short* __restrict__ xw1, unsigned short* __restrict__ xw2,
    float* __restrict__ s1, float* __restrict__ d1,
    float* __restrict__ s2, float* __restrict__ d2, int n)
{
    __shared__ float w1s[DIN * DOUT];   // 32 KB
    __shared__ float w2s[DIN * DOUT];   // 32 KB
    __shared__ float xs[16][DIN];       // 8 KB
    int tid = threadIdx.x;

    {   // stage W1, W2: 2048 float4 each, 8 per thread
        const float4* W14 = (const float4*)W1;
        const float4* W24 = (const float4*)W2;
        float4* w1s4 = (float4*)w1s;
        float4* w2s4 = (float4*)w2s;
        #pragma unroll
        for (int r = 0; r < 8; ++r) {
            int i = r * 256 + tid;
            w1s4[i] = W14[i];
            w2s4[i] = W24[i];
        }
    }
    int nb0 = blockIdx.x * 16;
    {   // stage x tile: 16 rows x 128 = 512 float4, 2 per thread
        const float4* x4 = (const float4*)(x + (size_t)nb0 * DIN);
        float4* xs4 = (float4*)&xs[0][0];
        int lim = (n - nb0) * (DIN / 4);
        if (lim > 512) lim = 512;
        #pragma unroll
        for (int r = 0; r < 2; ++r) {
            int i = r * 256 + tid;
            if (i < lim) xs4[i] = x4[i];
        }
    }
    __syncthreads();

    int wave = tid >> 6, lane = tid & 63;
    int nb = nb0 + wave * 4;
    float a1[4] = {0, 0, 0, 0}, a2[4] = {0, 0, 0, 0};
    #pragma unroll 4
    for (int k = 0; k < DIN; ++k) {
        float w1 = w1s[k * DOUT + lane];   // 2-way bank alias: free
        float w2 = w2s[k * DOUT + lane];
        #pragma unroll
        for (int m = 0; m < 4; ++m) {
            float xv = xs[wave * 4 + m][k];  // broadcast read: free
            a1[m] = fmaf(xv, w1, a1[m]);
            a2[m] = fmaf(xv, w2, a2[m]);
        }
    }
    float A1 = as1[lane], A2 = ad1[lane], A3 = as2[lane], A4 = ad2[lane];
    #pragma unroll
    for (int m = 0; m < 4; ++m) {
        int node = nb + m;
        if (node >= n) break;
        xw1[(size_t)node * DOUT + lane] = f2bf(a1[m]);
        xw2[(size_t)node * DOUT + lane] = f2bf(a2[m]);
        float v1 = a1[m] * A1, v2 = a1[m] * A2, v3 = a2[m] * A3, v4 = a2[m] * A4;
        #pragma unroll
        for (int off = 32; off; off >>= 1) {
            v1 += __shfl_xor(v1, off);
            v2 += __shfl_xor(v2, off);
            v3 += __shfl_xor(v3, off);
            v4 += __shfl_xor(v4, off);
        }
        if (lane == 0) { s1[node] = v1; d1[node] = v2; s2[node] = v3; d2[node] = v4; }
    }
}

// ---------------- CSR build over unified 2n segment space:
// segment i in [0,n)   : in-edges of node i  (fwd, grouped by dst)
// segment n+i          : out-edges of node i (rev, grouped by src)
__global__ __launch_bounds__(256) void hist_kernel(
    const int* __restrict__ src, const int* __restrict__ dst,
    int* __restrict__ deg, int e, int n)
{
    int t = blockIdx.x * 256 + threadIdx.x;
    if (t >= e) return;
    atomicAdd(&deg[dst[t]], 1);
    atomicAdd(&deg[n + src[t]], 1);
}

// per-1024-elem tile sums
__global__ __launch_bounds__(256) void scan_part_kernel(
    const int* __restrict__ deg, int* __restrict__ part, int n2)
{
    __shared__ int sm[256];
    int b = blockIdx.x, t = threadIdx.x;
    int base = b * 1024 + t * 4;
    int s = 0;
    #pragma unroll
    for (int k = 0; k < 4; ++k) { int i = base + k; if (i < n2) s += deg[i]; }
    sm[t] = s; __syncthreads();
    for (int o = 128; o; o >>= 1) { if (t < o) sm[t] += sm[t + o]; __syncthreads(); }
    if (t == 0) part[b] = sm[0];
}

// exclusive scan of tile sums (single block); also writes offs[n2] = total
__global__ __launch_bounds__(1024) void scan_mid_kernel(
    int* __restrict__ part, int nb, int* __restrict__ offs, int n2, int total)
{
    __shared__ int sm[1024];
    int t = threadIdx.x;
    int v = (t < nb) ? part[t] : 0;
    sm[t] = v; __syncthreads();
    for (int o = 1; o < 1024; o <<= 1) {
        int u = (t >= o) ? sm[t - o] : 0;
        __syncthreads();
        sm[t] += u;
        __syncthreads();
    }
    if (t < nb) part[t] = sm[t] - v;   // exclusive
    if (t == 0) offs[n2] = total;
}

// block-local exclusive scan + tile base -> offsets
__global__ __launch_bounds__(256) void scan_apply_kernel(
    const int* __restrict__ deg, const int* __restrict__ part,
    int* __restrict__ offs, int n2)
{
    __shared__ int sm[256];
    int b = blockIdx.x, t = threadIdx.x;
    int base = b * 1024 + t * 4;
    int d[4]; int s = 0;
    #pragma unroll
    for (int k = 0; k < 4; ++k) { int i = base + k; d[k] = (i < n2) ? deg[i] : 0; s += d[k]; }
    sm[t] = s; __syncthreads();
    for (int o = 1; o < 256; o <<= 1) {
        int u = (t >= o) ? sm[t - o] : 0;
        __syncthreads();
        sm[t] += u;
        __syncthreads();
    }
    int run = part[b] + sm[t] - s;
    #pragma unroll
    for (int k = 0; k < 4; ++k) {
        int i = base + k;
        if (i < n2) { offs[i] = run; run += d[k]; }
    }
}

__global__ __launch_bounds__(256) void fill_kernel(
    const int* __restrict__ src, const int* __restrict__ dst,
    const int* __restrict__ offs, int* __restrict__ cur,
    int* __restrict__ csr, int e, int n)
{
    int t = blockIdx.x * 256 + threadIdx.x;
    if (t >= e) return;
    int s = src[t], d = dst[t];
    int p = atomicAdd(&cur[d], 1);
    csr[offs[d] + p] = s;
    int q = atomicAdd(&cur[n + s], 1);
    csr[offs[n + s] + q] = d;
}

// ---------------- gather: 2 waves per node (one per direction).
// Lane-parallel chunked softmax: lane t handles edge c+t's score; broadcast
// p/j via readlane for the accumulate loop. One 256B atomicAdd per (node,dir).
__global__ __launch_bounds__(256) void gather_kernel(
    const int* __restrict__ offs, const int* __restrict__ csr,
    const float* __restrict__ s1, const float* __restrict__ d1,
    const float* __restrict__ s2, const float* __restrict__ d2,
    const unsigned short* __restrict__ xw1, const unsigned short* __restrict__ xw2,
    const float* __restrict__ b1, const float* __restrict__ b2,
    float* __restrict__ out, int n)
{
    int w = (blockIdx.x * 256 + threadIdx.x) >> 6;
    int lane = threadIdx.x & 63;
    if (w >= 2 * n) return;
    int i = w >> 1;
    int dir = w & 1;

    const float* sbuf = dir ? s2 : s1;
    const unsigned short* xw = dir ? xw2 : xw1;
    float dsc = dir ? d2[i] : d1[i];
    int base = dir ? n + i : i;
    int beg = offs[base], end = offs[base + 1];

    // self-loop seeds the running softmax
    float m = lrelu(sbuf[i] + dsc);
    float l = 1.0f;
    float acc = bf2f(xw[(size_t)i * DOUT + lane]);

    for (int c = beg; c < end; c += 64) {
        int cnt = end - c; if (cnt > 64) cnt = 64;
        int j = 0;
        float sc = -1e30f;
        if (lane < cnt) {
            j = csr[c + lane];
            sc = lrelu(sbuf[j] + dsc);
        }
        // wave max of chunk scores
        float cm = sc;
        #pragma unroll
        for (int off = 32; off; off >>= 1) cm = fmaxf(cm, __shfl_xor(cm, off));
        float mn = fmaxf(m, cm);
        float scale = __expf(m - mn);        // == 1.0 exactly when m >= cm
        float p = __expf(sc - mn);           // 0 for idle lanes (sc=-1e30)
        float ps = p;
        #pragma unroll
        for (int off = 32; off; off >>= 1) ps += __shfl_xor(ps, off);
        l = fmaf(l, scale, ps);
        acc *= scale;
        m = mn;
        #pragma unroll 4
        for (int t = 0; t < cnt; ++t) {
            float pt = readlane_f(p, t);
            int jt = __builtin_amdgcn_readlane(j, t);
            acc = fmaf(pt, bf2f(xw[(size_t)jt * DOUT + lane]), acc);
        }
    }
    float res = acc / (l + 1e-16f);
    float add;
    if (dir) add = ALPHA * res;
    else     add = (1.0f - ALPHA) * res + (1.0f - ALPHA) * b1[lane] + ALPHA * b2[lane];
    atomicAdd(&out[(size_t)i * DOUT + lane], add);
}

extern "C" void kernel_launch(void* const* d_in, const int* in_sizes, int n_in,
                              void* d_out, int out_size, void* d_ws, size_t ws_size,
                              hipStream_t stream) {
    const float* x   = (const float*)d_in[0];
    const int*   ei  = (const int*)d_in[1];
    const float* W1  = (const float*)d_in[2];
    const float* as1 = (const float*)d_in[3];
    const float* ad1 = (const float*)d_in[4];
    const float* b1  = (const float*)d_in[5];
    const float* W2  = (const float*)d_in[6];
    const float* as2 = (const float*)d_in[7];
    const float* ad2 = (const float*)d_in[8];
    const float* b2  = (const float*)d_in[9];
    float* out = (float*)d_out;

    int n = in_sizes[0] / DIN;   // 50000
    int e = in_sizes[1] / 2;     // 800000
    const int* src = ei;
    const int* dst = ei + e;
    int n2 = 2 * n;
    int nb = (n2 + 1023) / 1024;  // 98 tiles

    // workspace (32-bit words):
    // xw1[32n] xw2[32n] (bf16) s1[n] d1[n] s2[n] d2[n]
    // deg[2n] cur[2n] offs[2n+1] part[1024] csr[2e + pad]
    unsigned short* xw1 = (unsigned short*)d_ws;
    unsigned short* xw2 = xw1 + (size_t)n * DOUT;
    float* s1  = (float*)(xw2 + (size_t)n * DOUT);
    float* d1  = s1 + n;
    float* s2  = d1 + n;
    float* d2  = s2 + n;
    int* deg   = (int*)(d2 + n);
    int* cur   = deg + (size_t)n2;
    int* offs  = cur + (size_t)n2;
    int* part  = offs + (size_t)n2 + 1;
    int* csr   = part + 1024;

    hipMemsetAsync(deg, 0, (size_t)2 * n2 * sizeof(int), stream);      // deg + cur
    hipMemsetAsync(out, 0, (size_t)n * DOUT * sizeof(float), stream);

    proj_kernel<<<(n + 15) / 16, 256, 0, stream>>>(x, W1, W2, as1, ad1, as2, ad2,
                                                   xw1, xw2, s1, d1, s2, d2, n);

    hist_kernel<<<(e + 255) / 256, 256, 0, stream>>>(src, dst, deg, e, n);
    scan_part_kernel<<<nb, 256, 0, stream>>>(deg, part, n2);
    scan_mid_kernel<<<1, 1024, 0, stream>>>(part, nb, offs, n2, 2 * e);
    scan_apply_kernel<<<nb, 256, 0, stream>>>(deg, part, offs, n2);
    fill_kernel<<<(e + 255) / 256, 256, 0, stream>>>(src, dst, offs, cur, csr, e, n);

    long long gthreads = (long long)n2 * 64;
    int gblocks = (int)((gthreads + 255) / 256);
    gather_kernel<<<gblocks, 256, 0, stream>>>(offs, csr, s1, d1, s2, d2,
                                               xw1, xw2, b1, b2, out, n);
}

// Round 6
// 288.489 us; speedup vs baseline: 1.2015x; 1.2015x over previous
//
#include <hip/hip_runtime.h>

#define DIN 128
#define DOUT 64
#define NEG_SLOPE 0.2f
#define ALPHA 0.5f

__device__ __forceinline__ float lrelu(float x) { return x > 0.0f ? x : NEG_SLOPE * x; }

__device__ __forceinline__ unsigned short f2bf(float f) {
    unsigned u = __float_as_uint(f);
    unsigned r = (u + 0x7fffu + ((u >> 16) & 1u)) >> 16;
    return (unsigned short)r;
}
__device__ __forceinline__ float bf2f(unsigned short h) {
    return __uint_as_float((unsigned)h << 16);
}
__device__ __forceinline__ float readlane_f(float v, int l) {
    return __int_as_float(__builtin_amdgcn_readlane(__float_as_int(v), l));
}

// ---------------- proj: xw = x@W (bf16 out) + 4 per-node score dots (f32).
// Block = 256 thr (4 waves). W1+W2 in LDS (64 KB), x tile (16 rows) in LDS.
__global__ __launch_bounds__(256) void proj_kernel(
    const float* __restrict__ x,
    const float* __restrict__ W1, const float* __restrict__ W2,
    const float* __restrict__ as1, const float* __restrict__ ad1,
    const float* __restrict__ as2, const float* __restrict__ ad2,
    unsigned short* __restrict__ xw1, unsigned short* __restrict__ xw2,
    float* __restrict__ s1, float* __restrict__ d1,
    float* __restrict__ s2, float* __restrict__ d2, int n)
{
    __shared__ float w1s[DIN * DOUT];   // 32 KB
    __shared__ float w2s[DIN * DOUT];   // 32 KB
    __shared__ float xs[16][DIN];       // 8 KB
    int tid = threadIdx.x;

    {   // stage W1, W2: 2048 float4 each, 8 per thread
        const float4* W14 = (const float4*)W1;
        const float4* W24 = (const float4*)W2;
        float4* w1s4 = (float4*)w1s;
        float4* w2s4 = (float4*)w2s;
        #pragma unroll
        for (int r = 0; r < 8; ++r) {
            int i = r * 256 + tid;
            w1s4[i] = W14[i];
            w2s4[i] = W24[i];
        }
    }
    int nb0 = blockIdx.x * 16;
    {   // stage x tile: 16 rows x 128 = 512 float4, 2 per thread
        const float4* x4 = (const float4*)(x + (size_t)nb0 * DIN);
        float4* xs4 = (float4*)&xs[0][0];
        int lim = (n - nb0) * (DIN / 4);
        if (lim > 512) lim = 512;
        #pragma unroll
        for (int r = 0; r < 2; ++r) {
            int i = r * 256 + tid;
            if (i < lim) xs4[i] = x4[i];
        }
    }
    __syncthreads();

    int wave = tid >> 6, lane = tid & 63;
    int nb = nb0 + wave * 4;
    float a1[4] = {0, 0, 0, 0}, a2[4] = {0, 0, 0, 0};
    #pragma unroll 4
    for (int k = 0; k < DIN; ++k) {
        float w1 = w1s[k * DOUT + lane];   // 2-way bank alias: free
        float w2 = w2s[k * DOUT + lane];
        #pragma unroll
        for (int m = 0; m < 4; ++m) {
            float xv = xs[wave * 4 + m][k];  // broadcast read: free
            a1[m] = fmaf(xv, w1, a1[m]);
            a2[m] = fmaf(xv, w2, a2[m]);
        }
    }
    float A1 = as1[lane], A2 = ad1[lane], A3 = as2[lane], A4 = ad2[lane];
    #pragma unroll
    for (int m = 0; m < 4; ++m) {
        int node = nb + m;
        if (node >= n) break;
        xw1[(size_t)node * DOUT + lane] = f2bf(a1[m]);
        xw2[(size_t)node * DOUT + lane] = f2bf(a2[m]);
        float v1 = a1[m] * A1, v2 = a1[m] * A2, v3 = a2[m] * A3, v4 = a2[m] * A4;
        #pragma unroll
        for (int off = 32; off; off >>= 1) {
            v1 += __shfl_xor(v1, off);
            v2 += __shfl_xor(v2, off);
            v3 += __shfl_xor(v3, off);
            v4 += __shfl_xor(v4, off);
        }
        if (lane == 0) { s1[node] = v1; d1[node] = v2; s2[node] = v3; d2[node] = v4; }
    }
}

// ---------------- CSR build over unified 2n segment space:
// segment i in [0,n)   : in-edges of node i  (fwd, grouped by dst)
// segment n+i          : out-edges of node i (rev, grouped by src)
__global__ __launch_bounds__(256) void hist_kernel(
    const int* __restrict__ src, const int* __restrict__ dst,
    int* __restrict__ deg, int e, int n)
{
    int t = blockIdx.x * 256 + threadIdx.x;
    if (t >= e) return;
    atomicAdd(&deg[dst[t]], 1);
    atomicAdd(&deg[n + src[t]], 1);
}

// per-1024-elem tile sums
__global__ __launch_bounds__(256) void scan_part_kernel(
    const int* __restrict__ deg, int* __restrict__ part, int n2)
{
    __shared__ int sm[256];
    int b = blockIdx.x, t = threadIdx.x;
    int base = b * 1024 + t * 4;
    int s = 0;
    #pragma unroll
    for (int k = 0; k < 4; ++k) { int i = base + k; if (i < n2) s += deg[i]; }
    sm[t] = s; __syncthreads();
    for (int o = 128; o; o >>= 1) { if (t < o) sm[t] += sm[t + o]; __syncthreads(); }
    if (t == 0) part[b] = sm[0];
}

// exclusive scan of tile sums (single block); also writes offs[n2] = total
__global__ __launch_bounds__(1024) void scan_mid_kernel(
    int* __restrict__ part, int nb, int* __restrict__ offs, int n2, int total)
{
    __shared__ int sm[1024];
    int t = threadIdx.x;
    int v = (t < nb) ? part[t] : 0;
    sm[t] = v; __syncthreads();
    for (int o = 1; o < 1024; o <<= 1) {
        int u = (t >= o) ? sm[t - o] : 0;
        __syncthreads();
        sm[t] += u;
        __syncthreads();
    }
    if (t < nb) part[t] = sm[t] - v;   // exclusive
    if (t == 0) offs[n2] = total;
}

// block-local exclusive scan + tile base -> offsets
__global__ __launch_bounds__(256) void scan_apply_kernel(
    const int* __restrict__ deg, const int* __restrict__ part,
    int* __restrict__ offs, int n2)
{
    __shared__ int sm[256];
    int b = blockIdx.x, t = threadIdx.x;
    int base = b * 1024 + t * 4;
    int d[4]; int s = 0;
    #pragma unroll
    for (int k = 0; k < 4; ++k) { int i = base + k; d[k] = (i < n2) ? deg[i] : 0; s += d[k]; }
    sm[t] = s; __syncthreads();
    for (int o = 1; o < 256; o <<= 1) {
        int u = (t >= o) ? sm[t - o] : 0;
        __syncthreads();
        sm[t] += u;
        __syncthreads();
    }
    int run = part[b] + sm[t] - s;
    #pragma unroll
    for (int k = 0; k < 4; ++k) {
        int i = base + k;
        if (i < n2) { offs[i] = run; run += d[k]; }
    }
}

__global__ __launch_bounds__(256) void fill_kernel(
    const int* __restrict__ src, const int* __restrict__ dst,
    const int* __restrict__ offs, int* __restrict__ cur,
    int* __restrict__ csr, int e, int n)
{
    int t = blockIdx.x * 256 + threadIdx.x;
    if (t >= e) return;
    int s = src[t], d = dst[t];
    int p = atomicAdd(&cur[d], 1);
    csr[offs[d] + p] = s;
    int q = atomicAdd(&cur[n + s], 1);
    csr[offs[n + s] + q] = d;
}

// ---------------- gather: ONE wave per node, both directions fused.
// Lane-parallel chunk scores; accumulate with 2 independent fma chains per
// direction (4 concurrent row-load streams). Plain store, no atomics.
__global__ __launch_bounds__(256) void gather_kernel(
    const int* __restrict__ offs, const int* __restrict__ csr,
    const float* __restrict__ s1, const float* __restrict__ d1,
    const float* __restrict__ s2, const float* __restrict__ d2,
    const unsigned short* __restrict__ xw1, const unsigned short* __restrict__ xw2,
    const float* __restrict__ b1, const float* __restrict__ b2,
    float* __restrict__ out, int n)
{
    int i = (blockIdx.x * 256 + threadIdx.x) >> 6;
    int lane = threadIdx.x & 63;
    if (i >= n) return;

    float d1i = d1[i], d2i = d2[i];
    int cF = offs[i],     endF = offs[i + 1];
    int cR = offs[n + i], endR = offs[n + i + 1];

    // self-loop seeds both running softmaxes (p_self == 1 exactly)
    float mF = lrelu(s1[i] + d1i), lF = 1.0f;
    float mR = lrelu(s2[i] + d2i), lR = 1.0f;
    float aF0 = bf2f(xw1[(size_t)i * DOUT + lane]), aF1 = 0.0f;
    float aR0 = bf2f(xw2[(size_t)i * DOUT + lane]), aR1 = 0.0f;

    while (cF < endF || cR < endR) {
        int cntF = endF - cF; cntF = cntF < 0 ? 0 : (cntF > 64 ? 64 : cntF);
        int cntR = endR - cR; cntR = cntR < 0 ? 0 : (cntR > 64 ? 64 : cntR);

        int jF = 0, jR = 0;
        float scF = -1e30f, scR = -1e30f;
        if (lane < cntF) { jF = csr[cF + lane]; scF = lrelu(s1[jF] + d1i); }
        if (lane < cntR) { jR = csr[cR + lane]; scR = lrelu(s2[jR] + d2i); }

        // wave max of both chunks (independent reductions interleave)
        float cmF = scF, cmR = scR;
        #pragma unroll
        for (int off = 32; off; off >>= 1) {
            cmF = fmaxf(cmF, __shfl_xor(cmF, off));
            cmR = fmaxf(cmR, __shfl_xor(cmR, off));
        }
        float mnF = fmaxf(mF, cmF), mnR = fmaxf(mR, cmR);
        float sclF = __expf(mF - mnF), sclR = __expf(mR - mnR);  // ==1.0 when m>=cm
        float pF = __expf(scF - mnF), pR = __expf(scR - mnR);    // 0 for idle lanes
        float psF = pF, psR = pR;
        #pragma unroll
        for (int off = 32; off; off >>= 1) {
            psF += __shfl_xor(psF, off);
            psR += __shfl_xor(psR, off);
        }
        lF = fmaf(lF, sclF, psF);
        lR = fmaf(lR, sclR, psR);
        aF0 *= sclF; aF1 *= sclF;
        aR0 *= sclR; aR1 *= sclR;
        mF = mnF; mR = mnR;

        // fused accumulate: p==0 past each dir's cnt makes this predication-free
        int tmax = cntF > cntR ? cntF : cntR;
        int t = 0;
        for (; t + 2 <= tmax; t += 2) {
            float pF0 = readlane_f(pF, t), pF1 = readlane_f(pF, t + 1);
            int   jF0 = __builtin_amdgcn_readlane(jF, t);
            int   jF1 = __builtin_amdgcn_readlane(jF, t + 1);
            float pR0 = readlane_f(pR, t), pR1 = readlane_f(pR, t + 1);
            int   jR0 = __builtin_amdgcn_readlane(jR, t);
            int   jR1 = __builtin_amdgcn_readlane(jR, t + 1);
            aF0 = fmaf(pF0, bf2f(xw1[(size_t)jF0 * DOUT + lane]), aF0);
            aF1 = fmaf(pF1, bf2f(xw1[(size_t)jF1 * DOUT + lane]), aF1);
            aR0 = fmaf(pR0, bf2f(xw2[(size_t)jR0 * DOUT + lane]), aR0);
            aR1 = fmaf(pR1, bf2f(xw2[(size_t)jR1 * DOUT + lane]), aR1);
        }
        if (t < tmax) {
            float pF0 = readlane_f(pF, t);
            int   jF0 = __builtin_amdgcn_readlane(jF, t);
            float pR0 = readlane_f(pR, t);
            int   jR0 = __builtin_amdgcn_readlane(jR, t);
            aF0 = fmaf(pF0, bf2f(xw1[(size_t)jF0 * DOUT + lane]), aF0);
            aR0 = fmaf(pR0, bf2f(xw2[(size_t)jR0 * DOUT + lane]), aR0);
        }
        cF += cntF;
        cR += cntR;
    }

    float resF = (aF0 + aF1) / (lF + 1e-16f);
    float resR = (aR0 + aR1) / (lR + 1e-16f);
    out[(size_t)i * DOUT + lane] =
        (1.0f - ALPHA) * (resF + b1[lane]) + ALPHA * (resR + b2[lane]);
}

extern "C" void kernel_launch(void* const* d_in, const int* in_sizes, int n_in,
                              void* d_out, int out_size, void* d_ws, size_t ws_size,
                              hipStream_t stream) {
    const float* x   = (const float*)d_in[0];
    const int*   ei  = (const int*)d_in[1];
    const float* W1  = (const float*)d_in[2];
    const float* as1 = (const float*)d_in[3];
    const float* ad1 = (const float*)d_in[4];
    const float* b1  = (const float*)d_in[5];
    const float* W2  = (const float*)d_in[6];
    const float* as2 = (const float*)d_in[7];
    const float* ad2 = (const float*)d_in[8];
    const float* b2  = (const float*)d_in[9];
    float* out = (float*)d_out;

    int n = in_sizes[0] / DIN;   // 50000
    int e = in_sizes[1] / 2;     // 800000
    const int* src = ei;
    const int* dst = ei + e;
    int n2 = 2 * n;
    int nb = (n2 + 1023) / 1024;  // 98 tiles

    // workspace (32-bit words):
    // xw1[32n] xw2[32n] (bf16) s1[n] d1[n] s2[n] d2[n]
    // deg[2n] cur[2n] offs[2n+1] part[1024] csr[2e + pad]
    unsigned short* xw1 = (unsigned short*)d_ws;
    unsigned short* xw2 = xw1 + (size_t)n * DOUT;
    float* s1  = (float*)(xw2 + (size_t)n * DOUT);
    float* d1  = s1 + n;
    float* s2  = d1 + n;
    float* d2  = s2 + n;
    int* deg   = (int*)(d2 + n);
    int* cur   = deg + (size_t)n2;
    int* offs  = cur + (size_t)n2;
    int* part  = offs + (size_t)n2 + 1;
    int* csr   = part + 1024;

    hipMemsetAsync(deg, 0, (size_t)2 * n2 * sizeof(int), stream);      // deg + cur

    proj_kernel<<<(n + 15) / 16, 256, 0, stream>>>(x, W1, W2, as1, ad1, as2, ad2,
                                                   xw1, xw2, s1, d1, s2, d2, n);

    hist_kernel<<<(e + 255) / 256, 256, 0, stream>>>(src, dst, deg, e, n);
    scan_part_kernel<<<nb, 256, 0, stream>>>(deg, part, n2);
    scan_mid_kernel<<<1, 1024, 0, stream>>>(part, nb, offs, n2, 2 * e);
    scan_apply_kernel<<<nb, 256, 0, stream>>>(deg, part, offs, n2);
    fill_kernel<<<(e + 255) / 256, 256, 0, stream>>>(src, dst, offs, cur, csr, e, n);

    long long gthreads = (long long)n * 64;
    int gblocks = (int)((gthreads + 255) / 256);
    gather_kernel<<<gblocks, 256, 0, stream>>>(offs, csr, s1, d1, s2, d2,
                                               xw1, xw2, b1, b2, out, n);
}

// Round 7
// 192.122 us; speedup vs baseline: 1.8042x; 1.5016x over previous
//
#include <hip/hip_runtime.h>

#define DIN 128
#define DOUT 64
#define NEG_SLOPE 0.2f
#define ALPHA 0.5f
#define NBUK 1024   // coarse buckets: bucket = seg >> 7, covers 2n = 100000 segments
#define EPB  16384  // edges per block in binning passes

__device__ __forceinline__ float lrelu(float x) { return x > 0.0f ? x : NEG_SLOPE * x; }

__device__ __forceinline__ unsigned short f2bf(float f) {
    unsigned u = __float_as_uint(f);
    unsigned r = (u + 0x7fffu + ((u >> 16) & 1u)) >> 16;
    return (unsigned short)r;
}
__device__ __forceinline__ float bf2f(unsigned short h) {
    return __uint_as_float((unsigned)h << 16);
}
__device__ __forceinline__ float readlane_f(float v, int l) {
    return __int_as_float(__builtin_amdgcn_readlane(__float_as_int(v), l));
}

// ---------------- proj: xw = x@W (bf16 out) + 4 per-node score dots (f32).
__global__ __launch_bounds__(256) void proj_kernel(
    const float* __restrict__ x,
    const float* __restrict__ W1, const float* __restrict__ W2,
    const float* __restrict__ as1, const float* __restrict__ ad1,
    const float* __restrict__ as2, const float* __restrict__ ad2,
    unsigned short* __restrict__ xw1, unsigned short* __restrict__ xw2,
    float* __restrict__ s1, float* __restrict__ d1,
    float* __restrict__ s2, float* __restrict__ d2, int n)
{
    __shared__ float w1s[DIN * DOUT];   // 32 KB
    __shared__ float w2s[DIN * DOUT];   // 32 KB
    __shared__ float xs[16][DIN];       // 8 KB
    int tid = threadIdx.x;

    {
        const float4* W14 = (const float4*)W1;
        const float4* W24 = (const float4*)W2;
        float4* w1s4 = (float4*)w1s;
        float4* w2s4 = (float4*)w2s;
        #pragma unroll
        for (int r = 0; r < 8; ++r) {
            int i = r * 256 + tid;
            w1s4[i] = W14[i];
            w2s4[i] = W24[i];
        }
    }
    int nb0 = blockIdx.x * 16;
    {
        const float4* x4 = (const float4*)(x + (size_t)nb0 * DIN);
        float4* xs4 = (float4*)&xs[0][0];
        int lim = (n - nb0) * (DIN / 4);
        if (lim > 512) lim = 512;
        #pragma unroll
        for (int r = 0; r < 2; ++r) {
            int i = r * 256 + tid;
            if (i < lim) xs4[i] = x4[i];
        }
    }
    __syncthreads();

    int wave = tid >> 6, lane = tid & 63;
    int nb = nb0 + wave * 4;
    float a1[4] = {0, 0, 0, 0}, a2[4] = {0, 0, 0, 0};
    #pragma unroll 4
    for (int k = 0; k < DIN; ++k) {
        float w1 = w1s[k * DOUT + lane];
        float w2 = w2s[k * DOUT + lane];
        #pragma unroll
        for (int m = 0; m < 4; ++m) {
            float xv = xs[wave * 4 + m][k];
            a1[m] = fmaf(xv, w1, a1[m]);
            a2[m] = fmaf(xv, w2, a2[m]);
        }
    }
    float A1 = as1[lane], A2 = ad1[lane], A3 = as2[lane], A4 = ad2[lane];
    #pragma unroll
    for (int m = 0; m < 4; ++m) {
        int node = nb + m;
        if (node >= n) break;
        xw1[(size_t)node * DOUT + lane] = f2bf(a1[m]);
        xw2[(size_t)node * DOUT + lane] = f2bf(a2[m]);
        float v1 = a1[m] * A1, v2 = a1[m] * A2, v3 = a2[m] * A3, v4 = a2[m] * A4;
        #pragma unroll
        for (int off = 32; off; off >>= 1) {
            v1 += __shfl_xor(v1, off);
            v2 += __shfl_xor(v2, off);
            v3 += __shfl_xor(v3, off);
            v4 += __shfl_xor(v4, off);
        }
        if (lane == 0) { s1[node] = v1; d1[node] = v2; s2[node] = v3; d2[node] = v4; }
    }
}

// ---------------- pass A1: per-block bucket histogram (no global atomics)
__global__ __launch_bounds__(256) void binhist_kernel(
    const int* __restrict__ src, const int* __restrict__ dst,
    int* __restrict__ hist, int e, int n, int nblk)
{
    __shared__ int cnt[NBUK];
    int tid = threadIdx.x, blk = blockIdx.x;
    for (int b = tid; b < NBUK; b += 256) cnt[b] = 0;
    __syncthreads();
    int base = blk * EPB;
    for (int k = 0; k < EPB / 256; ++k) {
        int t = base + k * 256 + tid;
        if (t < e) {
            int s = src[t], d = dst[t];
            atomicAdd(&cnt[d >> 7], 1);          // fwd segment = dst
            atomicAdd(&cnt[(n + s) >> 7], 1);    // rev segment = n + src
        }
    }
    __syncthreads();
    for (int b = tid; b < NBUK; b += 256)
        hist[(size_t)b * nblk + blk] = cnt[b];   // bucket-major, block-minor
}

// ---------------- scan chain (generic exclusive scan of int array len L)
__global__ __launch_bounds__(256) void scan_part_kernel(
    const int* __restrict__ deg, int* __restrict__ part, int n2)
{
    __shared__ int sm[256];
    int b = blockIdx.x, t = threadIdx.x;
    int base = b * 1024 + t * 4;
    int s = 0;
    #pragma unroll
    for (int k = 0; k < 4; ++k) { int i = base + k; if (i < n2) s += deg[i]; }
    sm[t] = s; __syncthreads();
    for (int o = 128; o; o >>= 1) { if (t < o) sm[t] += sm[t + o]; __syncthreads(); }
    if (t == 0) part[b] = sm[0];
}

__global__ __launch_bounds__(1024) void scan_mid_kernel(
    int* __restrict__ part, int nb, int* __restrict__ offs, int n2, int total)
{
    __shared__ int sm[1024];
    int t = threadIdx.x;
    int v = (t < nb) ? part[t] : 0;
    sm[t] = v; __syncthreads();
    for (int o = 1; o < 1024; o <<= 1) {
        int u = (t >= o) ? sm[t - o] : 0;
        __syncthreads();
        sm[t] += u;
        __syncthreads();
    }
    if (t < nb) part[t] = sm[t] - v;
    if (t == 0) offs[n2] = total;
}

__global__ __launch_bounds__(256) void scan_apply_kernel(
    const int* __restrict__ deg, const int* __restrict__ part,
    int* __restrict__ offs, int n2)
{
    __shared__ int sm[256];
    int b = blockIdx.x, t = threadIdx.x;
    int base = b * 1024 + t * 4;
    int d[4]; int s = 0;
    #pragma unroll
    for (int k = 0; k < 4; ++k) { int i = base + k; d[k] = (i < n2) ? deg[i] : 0; s += d[k]; }
    sm[t] = s; __syncthreads();
    for (int o = 1; o < 256; o <<= 1) {
        int u = (t >= o) ? sm[t - o] : 0;
        __syncthreads();
        sm[t] += u;
        __syncthreads();
    }
    int run = part[b] + sm[t] - s;
    #pragma unroll
    for (int k = 0; k < 4; ++k) {
        int i = base + k;
        if (i < n2) { offs[i] = run; run += d[k]; }
    }
}

// ---------------- pass A3: bin edges into per-(block,bucket) private chunks.
// staging entry: (seg&127)<<16 | neighbor   (n = 50000 < 65536 fits 16 bits)
__global__ __launch_bounds__(256) void binscatter_kernel(
    const int* __restrict__ src, const int* __restrict__ dst,
    const int* __restrict__ hscan, unsigned* __restrict__ staging,
    int e, int n, int nblk)
{
    __shared__ int cur[NBUK];
    int tid = threadIdx.x, blk = blockIdx.x;
    for (int b = tid; b < NBUK; b += 256)
        cur[b] = hscan[(size_t)b * nblk + blk];
    __syncthreads();
    int base = blk * EPB;
    for (int k = 0; k < EPB / 256; ++k) {
        int t = base + k * 256 + tid;
        if (t < e) {
            int s = src[t], d = dst[t];
            int pF = atomicAdd(&cur[d >> 7], 1);
            staging[pF] = ((unsigned)(d & 127) << 16) | (unsigned)s;
            int segR = n + s;
            int pR = atomicAdd(&cur[segR >> 7], 1);
            staging[pR] = ((unsigned)(segR & 127) << 16) | (unsigned)d;
        }
    }
}

// ---------------- pass B: one block per bucket. LDS 128-seg count + scan,
// write offs (coalesced) and csr (scatter within hot single-XCD ~8KB span).
__global__ __launch_bounds__(256) void buildcsr_kernel(
    const int* __restrict__ hscan, const unsigned* __restrict__ staging,
    int* __restrict__ csr, int* __restrict__ offs,
    int n2, int e2, int nblk)
{
    __shared__ int segcnt[128];
    __shared__ int segoff[128];
    int b = blockIdx.x, tid = threadIdx.x;
    int lo = hscan[(size_t)b * nblk];
    int hi = hscan[(size_t)(b + 1) * nblk];   // b+1 <= 782 < NBUK; empty tail buckets give e2
    if (tid < 128) segcnt[tid] = 0;
    __syncthreads();
    for (int idx = lo + tid; idx < hi; idx += 256)
        atomicAdd(&segcnt[staging[idx] >> 16], 1);
    __syncthreads();
    if (tid < 64) {   // wave 0: exclusive scan of 128 counts
        int a = segcnt[2 * tid], c = segcnt[2 * tid + 1];
        int pair = a + c;
        int inc = pair;
        #pragma unroll
        for (int off = 1; off < 64; off <<= 1) {
            int u = __shfl_up(inc, off);
            if (tid >= off) inc += u;
        }
        int excl = inc - pair;
        segoff[2 * tid] = excl;
        segoff[2 * tid + 1] = excl + a;
    }
    __syncthreads();
    if (tid < 128) {
        int seg = (b << 7) + tid;
        if (seg < n2) offs[seg] = lo + segoff[tid];
        segcnt[tid] = segoff[tid];   // reuse as running cursors
    }
    if (b == gridDim.x - 1 && tid == 0) offs[n2] = e2;
    __syncthreads();
    for (int idx = lo + tid; idx < hi; idx += 256) {
        unsigned st = staging[idx];          // L2-hot re-read
        int pos = atomicAdd(&segcnt[st >> 16], 1);
        csr[lo + pos] = (int)(st & 0xFFFFu);
    }
}

// ---------------- gather: ONE wave per node, both directions fused.
__global__ __launch_bounds__(256) void gather_kernel(
    const int* __restrict__ offs, const int* __restrict__ csr,
    const float* __restrict__ s1, const float* __restrict__ d1,
    const float* __restrict__ s2, const float* __restrict__ d2,
    const unsigned short* __restrict__ xw1, const unsigned short* __restrict__ xw2,
    const float* __restrict__ b1, const float* __restrict__ b2,
    float* __restrict__ out, int n)
{
    int i = (blockIdx.x * 256 + threadIdx.x) >> 6;
    int lane = threadIdx.x & 63;
    if (i >= n) return;

    float d1i = d1[i], d2i = d2[i];
    int cF = offs[i],     endF = offs[i + 1];
    int cR = offs[n + i], endR = offs[n + i + 1];

    float mF = lrelu(s1[i] + d1i), lF = 1.0f;
    float mR = lrelu(s2[i] + d2i), lR = 1.0f;
    float aF0 = bf2f(xw1[(size_t)i * DOUT + lane]), aF1 = 0.0f;
    float aR0 = bf2f(xw2[(size_t)i * DOUT + lane]), aR1 = 0.0f;

    while (cF < endF || cR < endR) {
        int cntF = endF - cF; cntF = cntF < 0 ? 0 : (cntF > 64 ? 64 : cntF);
        int cntR = endR - cR; cntR = cntR < 0 ? 0 : (cntR > 64 ? 64 : cntR);

        int jF = 0, jR = 0;
        float scF = -1e30f, scR = -1e30f;
        if (lane < cntF) { jF = csr[cF + lane]; scF = lrelu(s1[jF] + d1i); }
        if (lane < cntR) { jR = csr[cR + lane]; scR = lrelu(s2[jR] + d2i); }

        float cmF = scF, cmR = scR;
        #pragma unroll
        for (int off = 32; off; off >>= 1) {
            cmF = fmaxf(cmF, __shfl_xor(cmF, off));
            cmR = fmaxf(cmR, __shfl_xor(cmR, off));
        }
        float mnF = fmaxf(mF, cmF), mnR = fmaxf(mR, cmR);
        float sclF = __expf(mF - mnF), sclR = __expf(mR - mnR);
        float pF = __expf(scF - mnF), pR = __expf(scR - mnR);
        float psF = pF, psR = pR;
        #pragma unroll
        for (int off = 32; off; off >>= 1) {
            psF += __shfl_xor(psF, off);
            psR += __shfl_xor(psR, off);
        }
        lF = fmaf(lF, sclF, psF);
        lR = fmaf(lR, sclR, psR);
        aF0 *= sclF; aF1 *= sclF;
        aR0 *= sclR; aR1 *= sclR;
        mF = mnF; mR = mnR;

        int tmax = cntF > cntR ? cntF : cntR;
        int t = 0;
        for (; t + 2 <= tmax; t += 2) {
            float pF0 = readlane_f(pF, t), pF1 = readlane_f(pF, t + 1);
            int   jF0 = __builtin_amdgcn_readlane(jF, t);
            int   jF1 = __builtin_amdgcn_readlane(jF, t + 1);
            float pR0 = readlane_f(pR, t), pR1 = readlane_f(pR, t + 1);
            int   jR0 = __builtin_amdgcn_readlane(jR, t);
            int   jR1 = __builtin_amdgcn_readlane(jR, t + 1);
            aF0 = fmaf(pF0, bf2f(xw1[(size_t)jF0 * DOUT + lane]), aF0);
            aF1 = fmaf(pF1, bf2f(xw1[(size_t)jF1 * DOUT + lane]), aF1);
            aR0 = fmaf(pR0, bf2f(xw2[(size_t)jR0 * DOUT + lane]), aR0);
            aR1 = fmaf(pR1, bf2f(xw2[(size_t)jR1 * DOUT + lane]), aR1);
        }
        if (t < tmax) {
            float pF0 = readlane_f(pF, t);
            int   jF0 = __builtin_amdgcn_readlane(jF, t);
            float pR0 = readlane_f(pR, t);
            int   jR0 = __builtin_amdgcn_readlane(jR, t);
            aF0 = fmaf(pF0, bf2f(xw1[(size_t)jF0 * DOUT + lane]), aF0);
            aR0 = fmaf(pR0, bf2f(xw2[(size_t)jR0 * DOUT + lane]), aR0);
        }
        cF += cntF;
        cR += cntR;
    }

    float resF = (aF0 + aF1) / (lF + 1e-16f);
    float resR = (aR0 + aR1) / (lR + 1e-16f);
    out[(size_t)i * DOUT + lane] =
        (1.0f - ALPHA) * (resF + b1[lane]) + ALPHA * (resR + b2[lane]);
}

extern "C" void kernel_launch(void* const* d_in, const int* in_sizes, int n_in,
                              void* d_out, int out_size, void* d_ws, size_t ws_size,
                              hipStream_t stream) {
    const float* x   = (const float*)d_in[0];
    const int*   ei  = (const int*)d_in[1];
    const float* W1  = (const float*)d_in[2];
    const float* as1 = (const float*)d_in[3];
    const float* ad1 = (const float*)d_in[4];
    const float* b1  = (const float*)d_in[5];
    const float* W2  = (const float*)d_in[6];
    const float* as2 = (const float*)d_in[7];
    const float* ad2 = (const float*)d_in[8];
    const float* b2  = (const float*)d_in[9];
    float* out = (float*)d_out;

    int n = in_sizes[0] / DIN;   // 50000  (must be < 65536 for 16-bit staging pack)
    int e = in_sizes[1] / 2;     // 800000
    const int* src = ei;
    const int* dst = ei + e;
    int n2 = 2 * n;
    int e2 = 2 * e;
    int nblk = (e + EPB - 1) / EPB;              // 49 binning blocks
    int L = NBUK * nblk;                         // 50176 hist entries
    int ntile = (L + 1023) / 1024;               // 49 scan tiles
    int nbuk_eff = (n2 + 127) >> 7;              // 782 non-empty buckets

    // workspace (32-bit words):
    // xw1[32n] xw2[32n] (bf16) s1 d1 s2 d2 [n each]
    // hist[L] hscan[L+1] part[1024] offs[n2+1] csr[e2] staging[e2]
    unsigned short* xw1 = (unsigned short*)d_ws;
    unsigned short* xw2 = xw1 + (size_t)n * DOUT;
    float* s1  = (float*)(xw2 + (size_t)n * DOUT);
    float* d1  = s1 + n;
    float* s2  = d1 + n;
    float* d2  = s2 + n;
    int* hist  = (int*)(d2 + n);
    int* hscan = hist + (size_t)L;
    int* part  = hscan + (size_t)L + 1;
    int* offs  = part + 1024;
    int* csr   = offs + (size_t)n2 + 1;
    unsigned* staging = (unsigned*)(csr + (size_t)e2);

    proj_kernel<<<(n + 15) / 16, 256, 0, stream>>>(x, W1, W2, as1, ad1, as2, ad2,
                                                   xw1, xw2, s1, d1, s2, d2, n);

    binhist_kernel<<<nblk, 256, 0, stream>>>(src, dst, hist, e, n, nblk);
    scan_part_kernel<<<ntile, 256, 0, stream>>>(hist, part, L);
    scan_mid_kernel<<<1, 1024, 0, stream>>>(part, ntile, hscan, L, e2);
    scan_apply_kernel<<<ntile, 256, 0, stream>>>(hist, part, hscan, L);
    binscatter_kernel<<<nblk, 256, 0, stream>>>(src, dst, hscan, staging, e, n, nblk);
    buildcsr_kernel<<<nbuk_eff, 256, 0, stream>>>(hscan, staging, csr, offs, n2, e2, nblk);

    long long gthreads = (long long)n * 64;
    int gblocks = (int)((gthreads + 255) / 256);
    gather_kernel<<<gblocks, 256, 0, stream>>>(offs, csr, s1, d1, s2, d2,
                                               xw1, xw2, b1, b2, out, n);
}

// Round 9
// 167.733 us; speedup vs baseline: 2.0665x; 1.1454x over previous
//
#include <hip/hip_runtime.h>

#define DIN 128
#define DOUT 64
#define NEG_SLOPE 0.2f
#define ALPHA 0.5f
#define NBUK 1024   // coarse buckets: bucket = seg >> 7, covers 2n = 100000 segments
#define EPB  16384  // edges per block in binning passes

typedef __attribute__((ext_vector_type(8))) short bf16x8;
typedef __attribute__((ext_vector_type(4))) float f32x4;

__device__ __forceinline__ float lrelu(float x) { return x > 0.0f ? x : NEG_SLOPE * x; }

__device__ __forceinline__ unsigned short f2bf(float f) {
    unsigned u = __float_as_uint(f);
    unsigned r = (u + 0x7fffu + ((u >> 16) & 1u)) >> 16;
    return (unsigned short)r;
}
__device__ __forceinline__ float bf2f(unsigned short h) {
    return __uint_as_float((unsigned)h << 16);
}
__device__ __forceinline__ float readlane_f(float v, int l) {
    return __int_as_float(__builtin_amdgcn_readlane(__float_as_int(v), l));
}

// ---------------- wfrag: bake W1,W2 into MFMA B-fragment order, split hi/lo.
// slot k-map (shared by A and B, any consistent bijection is valid):
//   k = kk*32 + (lane>>4)*8 + j,  n-col = t*16 + (lane&15)
// layout: wf[ ((mat*2+hl)*16 + kk*4 + t) * 512 + lane*8 + j ]
__global__ __launch_bounds__(64) void wfrag_kernel(
    const float* __restrict__ W1, const float* __restrict__ W2,
    unsigned short* __restrict__ wf)
{
    int l = threadIdx.x;
    int g = l >> 4, c = l & 15;
    for (int mat = 0; mat < 2; ++mat) {
        const float* W = mat ? W2 : W1;
        for (int kk = 0; kk < 4; ++kk) {
            for (int t = 0; t < 4; ++t) {
                #pragma unroll
                for (int j = 0; j < 8; ++j) {
                    float w = W[(kk * 32 + g * 8 + j) * DOUT + t * 16 + c];
                    unsigned short hi = f2bf(w);
                    unsigned short lo = f2bf(w - bf2f(hi));
                    wf[(size_t)(((mat * 2 + 0) * 16 + kk * 4 + t) * 512) + l * 8 + j] = hi;
                    wf[(size_t)(((mat * 2 + 1) * 16 + kk * 4 + t) * 512) + l * 8 + j] = lo;
                }
            }
        }
    }
}

// ---------------- proj via MFMA: one wave per 16-node tile, no LDS.
// xw = x@W via (xhi+xlo)(Whi+Wlo) ~ hi*hi + lo*hi + hi*lo  (f32 accum).
// C/D layout: col = lane&15, row = (lane>>4)*4 + reg  [m89 verified].
__global__ __launch_bounds__(256) void proj_kernel(
    const float* __restrict__ x, const unsigned short* __restrict__ wf,
    const float* __restrict__ as1, const float* __restrict__ ad1,
    const float* __restrict__ as2, const float* __restrict__ ad2,
    unsigned short* __restrict__ xw1, unsigned short* __restrict__ xw2,
    float* __restrict__ s1, float* __restrict__ d1,
    float* __restrict__ s2, float* __restrict__ d2, int n)
{
    int ntiles = (n + 15) >> 4;
    int tile = blockIdx.x * 4 + (threadIdx.x >> 6);
    if (tile >= ntiles) return;
    int l = threadIdx.x & 63;
    int g = l >> 4, c = l & 15;

    int arow = tile * 16 + c;
    if (arow >= n) arow = n - 1;   // clamp: stores are guarded

    // A fragments (x rows), split hi/lo
    bf16x8 ahi[4], alo[4];
    const float* xr = x + (size_t)arow * DIN + g * 8;
    #pragma unroll
    for (int kk = 0; kk < 4; ++kk) {
        float4 v0 = *(const float4*)(xr + kk * 32);
        float4 v1 = *(const float4*)(xr + kk * 32 + 4);
        float xv[8] = {v0.x, v0.y, v0.z, v0.w, v1.x, v1.y, v1.z, v1.w};
        #pragma unroll
        for (int j = 0; j < 8; ++j) {
            unsigned short hi = f2bf(xv[j]);
            unsigned short lo = f2bf(xv[j] - bf2f(hi));
            ahi[kk][j] = (short)hi;
            alo[kk][j] = (short)lo;
        }
    }

    float vs1[4] = {0, 0, 0, 0}, vd1[4] = {0, 0, 0, 0};
    float vs2[4] = {0, 0, 0, 0}, vd2[4] = {0, 0, 0, 0};
    const bf16x8* wfv = (const bf16x8*)wf;   // [(mat2hl)*16 + kk*4+t]*64 + lane

    #pragma unroll
    for (int t = 0; t < 4; ++t) {
        f32x4 C1 = {0.f, 0.f, 0.f, 0.f}, C2 = {0.f, 0.f, 0.f, 0.f};
        #pragma unroll
        for (int kk = 0; kk < 4; ++kk) {
            bf16x8 bh1 = wfv[(size_t)((0 * 16 + kk * 4 + t) * 64) + l];
            bf16x8 bl1 = wfv[(size_t)((1 * 16 + kk * 4 + t) * 64) + l];
            bf16x8 bh2 = wfv[(size_t)((2 * 16 + kk * 4 + t) * 64) + l];
            bf16x8 bl2 = wfv[(size_t)((3 * 16 + kk * 4 + t) * 64) + l];
            C1 = __builtin_amdgcn_mfma_f32_16x16x32_bf16(ahi[kk], bh1, C1, 0, 0, 0);
            C1 = __builtin_amdgcn_mfma_f32_16x16x32_bf16(alo[kk], bh1, C1, 0, 0, 0);
            C1 = __builtin_amdgcn_mfma_f32_16x16x32_bf16(ahi[kk], bl1, C1, 0, 0, 0);
            C2 = __builtin_amdgcn_mfma_f32_16x16x32_bf16(ahi[kk], bh2, C2, 0, 0, 0);
            C2 = __builtin_amdgcn_mfma_f32_16x16x32_bf16(alo[kk], bh2, C2, 0, 0, 0);
            C2 = __builtin_amdgcn_mfma_f32_16x16x32_bf16(ahi[kk], bl2, C2, 0, 0, 0);
        }
        float a1v = as1[t * 16 + c], a2v = ad1[t * 16 + c];
        float a3v = as2[t * 16 + c], a4v = ad2[t * 16 + c];
        #pragma unroll
        for (int r = 0; r < 4; ++r) {
            vs1[r] = fmaf(C1[r], a1v, vs1[r]);
            vd1[r] = fmaf(C1[r], a2v, vd1[r]);
            vs2[r] = fmaf(C2[r], a3v, vs2[r]);
            vd2[r] = fmaf(C2[r], a4v, vd2[r]);
        }
        #pragma unroll
        for (int r = 0; r < 4; ++r) {
            int node = tile * 16 + g * 4 + r;
            if (node < n) {
                xw1[(size_t)node * DOUT + t * 16 + c] = f2bf(C1[r]);
                xw2[(size_t)node * DOUT + t * 16 + c] = f2bf(C2[r]);
            }
        }
    }
    // reduce scores across the 16 lanes of each row-group
    #pragma unroll
    for (int off = 1; off < 16; off <<= 1) {
        #pragma unroll
        for (int r = 0; r < 4; ++r) {
            vs1[r] += __shfl_xor(vs1[r], off);
            vd1[r] += __shfl_xor(vd1[r], off);
            vs2[r] += __shfl_xor(vs2[r], off);
            vd2[r] += __shfl_xor(vd2[r], off);
        }
    }
    if (c == 0) {
        #pragma unroll
        for (int r = 0; r < 4; ++r) {
            int node = tile * 16 + g * 4 + r;
            if (node < n) {
                s1[node] = vs1[r]; d1[node] = vd1[r];
                s2[node] = vs2[r]; d2[node] = vd2[r];
            }
        }
    }
}

// ---------------- pass A1: per-block bucket histogram (no global atomics)
__global__ __launch_bounds__(256) void binhist_kernel(
    const int* __restrict__ src, const int* __restrict__ dst,
    int* __restrict__ hist, int e, int n, int nblk)
{
    __shared__ int cnt[NBUK];
    int tid = threadIdx.x, blk = blockIdx.x;
    for (int b = tid; b < NBUK; b += 256) cnt[b] = 0;
    __syncthreads();
    int base = blk * EPB;
    for (int k = 0; k < EPB / 256; ++k) {
        int t = base + k * 256 + tid;
        if (t < e) {
            int s = src[t], d = dst[t];
            atomicAdd(&cnt[d >> 7], 1);
            atomicAdd(&cnt[(n + s) >> 7], 1);
        }
    }
    __syncthreads();
    for (int b = tid; b < NBUK; b += 256)
        hist[(size_t)b * nblk + blk] = cnt[b];
}

// ---------------- scan chain
__global__ __launch_bounds__(256) void scan_part_kernel(
    const int* __restrict__ deg, int* __restrict__ part, int n2)
{
    __shared__ int sm[256];
    int b = blockIdx.x, t = threadIdx.x;
    int base = b * 1024 + t * 4;
    int s = 0;
    #pragma unroll
    for (int k = 0; k < 4; ++k) { int i = base + k; if (i < n2) s += deg[i]; }
    sm[t] = s; __syncthreads();
    for (int o = 128; o; o >>= 1) { if (t < o) sm[t] += sm[t + o]; __syncthreads(); }
    if (t == 0) part[b] = sm[0];
}

__global__ __launch_bounds__(1024) void scan_mid_kernel(
    int* __restrict__ part, int nb, int* __restrict__ offs, int n2, int total)
{
    __shared__ int sm[1024];
    int t = threadIdx.x;
    int v = (t < nb) ? part[t] : 0;
    sm[t] = v; __syncthreads();
    for (int o = 1; o < 1024; o <<= 1) {
        int u = (t >= o) ? sm[t - o] : 0;
        __syncthreads();
        sm[t] += u;
        __syncthreads();
    }
    if (t < nb) part[t] = sm[t] - v;
    if (t == 0) offs[n2] = total;
}

__global__ __launch_bounds__(256) void scan_apply_kernel(
    const int* __restrict__ deg, const int* __restrict__ part,
    int* __restrict__ offs, int n2)
{
    __shared__ int sm[256];
    int b = blockIdx.x, t = threadIdx.x;
    int base = b * 1024 + t * 4;
    int d[4]; int s = 0;
    #pragma unroll
    for (int k = 0; k < 4; ++k) { int i = base + k; d[k] = (i < n2) ? deg[i] : 0; s += d[k]; }
    sm[t] = s; __syncthreads();
    for (int o = 1; o < 256; o <<= 1) {
        int u = (t >= o) ? sm[t - o] : 0;
        __syncthreads();
        sm[t] += u;
        __syncthreads();
    }
    int run = part[b] + sm[t] - s;
    #pragma unroll
    for (int k = 0; k < 4; ++k) {
        int i = base + k;
        if (i < n2) { offs[i] = run; run += d[k]; }
    }
}

// ---------------- pass A3: bin edges into per-(block,bucket) private chunks.
__global__ __launch_bounds__(256) void binscatter_kernel(
    const int* __restrict__ src, const int* __restrict__ dst,
    const int* __restrict__ hscan, unsigned* __restrict__ staging,
    int e, int n, int nblk)
{
    __shared__ int cur[NBUK];
    int tid = threadIdx.x, blk = blockIdx.x;
    for (int b = tid; b < NBUK; b += 256)
        cur[b] = hscan[(size_t)b * nblk + blk];
    __syncthreads();
    int base = blk * EPB;
    for (int k = 0; k < EPB / 256; ++k) {
        int t = base + k * 256 + tid;
        if (t < e) {
            int s = src[t], d = dst[t];
            int pF = atomicAdd(&cur[d >> 7], 1);
            staging[pF] = ((unsigned)(d & 127) << 16) | (unsigned)s;
            int segR = n + s;
            int pR = atomicAdd(&cur[segR >> 7], 1);
            staging[pR] = ((unsigned)(segR & 127) << 16) | (unsigned)d;
        }
    }
}

// ---------------- pass B: one block per bucket -> offs + csr
__global__ __launch_bounds__(256) void buildcsr_kernel(
    const int* __restrict__ hscan, const unsigned* __restrict__ staging,
    int* __restrict__ csr, int* __restrict__ offs,
    int n2, int e2, int nblk)
{
    __shared__ int segcnt[128];
    __shared__ int segoff[128];
    int b = blockIdx.x, tid = threadIdx.x;
    int lo = hscan[(size_t)b * nblk];
    int hi = hscan[(size_t)(b + 1) * nblk];
    if (tid < 128) segcnt[tid] = 0;
    __syncthreads();
    for (int idx = lo + tid; idx < hi; idx += 256)
        atomicAdd(&segcnt[staging[idx] >> 16], 1);
    __syncthreads();
    if (tid < 64) {
        int a = segcnt[2 * tid], c = segcnt[2 * tid + 1];
        int pair = a + c;
        int inc = pair;
        #pragma unroll
        for (int off = 1; off < 64; off <<= 1) {
            int u = __shfl_up(inc, off);
            if (tid >= off) inc += u;
        }
        int excl = inc - pair;
        segoff[2 * tid] = excl;
        segoff[2 * tid + 1] = excl + a;
    }
    __syncthreads();
    if (tid < 128) {
        int seg = (b << 7) + tid;
        if (seg < n2) offs[seg] = lo + segoff[tid];
        segcnt[tid] = segoff[tid];
    }
    if (b == gridDim.x - 1 && tid == 0) offs[n2] = e2;
    __syncthreads();
    for (int idx = lo + tid; idx < hi; idx += 256) {
        unsigned st = staging[idx];
        int pos = atomicAdd(&segcnt[st >> 16], 1);
        csr[lo + pos] = (int)(st & 0xFFFFu);
    }
}

// ---------------- gather: ONE wave per node, both directions fused.
__global__ __launch_bounds__(256) void gather_kernel(
    const int* __restrict__ offs, const int* __restrict__ csr,
    const float* __restrict__ s1, const float* __restrict__ d1,
    const float* __restrict__ s2, const float* __restrict__ d2,
    const unsigned short* __restrict__ xw1, const unsigned short* __restrict__ xw2,
    const float* __restrict__ b1, const float* __restrict__ b2,
    float* __restrict__ out, int n)
{
    int i = (blockIdx.x * 256 + threadIdx.x) >> 6;
    int lane = threadIdx.x & 63;
    if (i >= n) return;

    float d1i = d1[i], d2i = d2[i];
    int cF = offs[i],     endF = offs[i + 1];
    int cR = offs[n + i], endR = offs[n + i + 1];

    float mF = lrelu(s1[i] + d1i), lF = 1.0f;
    float mR = lrelu(s2[i] + d2i), lR = 1.0f;
    float aF0 = bf2f(xw1[(size_t)i * DOUT + lane]), aF1 = 0.0f;
    float aR0 = bf2f(xw2[(size_t)i * DOUT + lane]), aR1 = 0.0f;

    while (cF < endF || cR < endR) {
        int cntF = endF - cF; cntF = cntF < 0 ? 0 : (cntF > 64 ? 64 : cntF);
        int cntR = endR - cR; cntR = cntR < 0 ? 0 : (cntR > 64 ? 64 : cntR);

        int jF = 0, jR = 0;
        float scF = -1e30f, scR = -1e30f;
        if (lane < cntF) { jF = csr[cF + lane]; scF = lrelu(s1[jF] + d1i); }
        if (lane < cntR) { jR = csr[cR + lane]; scR = lrelu(s2[jR] + d2i); }

        float cmF = scF, cmR = scR;
        #pragma unroll
        for (int off = 32; off; off >>= 1) {
            cmF = fmaxf(cmF, __shfl_xor(cmF, off));
            cmR = fmaxf(cmR, __shfl_xor(cmR, off));
        }
        float mnF = fmaxf(mF, cmF), mnR = fmaxf(mR, cmR);
        float sclF = __expf(mF - mnF), sclR = __expf(mR - mnR);
        float pF = __expf(scF - mnF), pR = __expf(scR - mnR);
        float psF = pF, psR = pR;
        #pragma unroll
        for (int off = 32; off; off >>= 1) {
            psF += __shfl_xor(psF, off);
            psR += __shfl_xor(psR, off);
        }
        lF = fmaf(lF, sclF, psF);
        lR = fmaf(lR, sclR, psR);
        aF0 *= sclF; aF1 *= sclF;
        aR0 *= sclR; aR1 *= sclR;
        mF = mnF; mR = mnR;

        int tmax = cntF > cntR ? cntF : cntR;
        int t = 0;
        for (; t + 2 <= tmax; t += 2) {
            float pF0 = readlane_f(pF, t), pF1 = readlane_f(pF, t + 1);
            int   jF0 = __builtin_amdgcn_readlane(jF, t);
            int   jF1 = __builtin_amdgcn_readlane(jF, t + 1);
            float pR0 = readlane_f(pR, t), pR1 = readlane_f(pR, t + 1);
            int   jR0 = __builtin_amdgcn_readlane(jR, t);
            int   jR1 = __builtin_amdgcn_readlane(jR, t + 1);
            aF0 = fmaf(pF0, bf2f(xw1[(size_t)jF0 * DOUT + lane]), aF0);
            aF1 = fmaf(pF1, bf2f(xw1[(size_t)jF1 * DOUT + lane]), aF1);
            aR0 = fmaf(pR0, bf2f(xw2[(size_t)jR0 * DOUT + lane]), aR0);
            aR1 = fmaf(pR1, bf2f(xw2[(size_t)jR1 * DOUT + lane]), aR1);
        }
        if (t < tmax) {
            float pF0 = readlane_f(pF, t);
            int   jF0 = __builtin_amdgcn_readlane(jF, t);
            float pR0 = readlane_f(pR, t);
            int   jR0 = __builtin_amdgcn_readlane(jR, t);
            aF0 = fmaf(pF0, bf2f(xw1[(size_t)jF0 * DOUT + lane]), aF0);
            aR0 = fmaf(pR0, bf2f(xw2[(size_t)jR0 * DOUT + lane]), aR0);
        }
        cF += cntF;
        cR += cntR;
    }

    float resF = (aF0 + aF1) / (lF + 1e-16f);
    float resR = (aR0 + aR1) / (lR + 1e-16f);
    out[(size_t)i * DOUT + lane] =
        (1.0f - ALPHA) * (resF + b1[lane]) + ALPHA * (resR + b2[lane]);
}

extern "C" void kernel_launch(void* const* d_in, const int* in_sizes, int n_in,
                              void* d_out, int out_size, void* d_ws, size_t ws_size,
                              hipStream_t stream) {
    const float* x   = (const float*)d_in[0];
    const int*   ei  = (const int*)d_in[1];
    const float* W1  = (const float*)d_in[2];
    const float* as1 = (const float*)d_in[3];
    const float* ad1 = (const float*)d_in[4];
    const float* b1  = (const float*)d_in[5];
    const float* W2  = (const float*)d_in[6];
    const float* as2 = (const float*)d_in[7];
    const float* ad2 = (const float*)d_in[8];
    const float* b2  = (const float*)d_in[9];
    float* out = (float*)d_out;

    int n = in_sizes[0] / DIN;   // 50000  (< 65536 for 16-bit staging pack)
    int e = in_sizes[1] / 2;     // 800000
    const int* src = ei;
    const int* dst = ei + e;
    int n2 = 2 * n;
    int e2 = 2 * e;
    int nblk = (e + EPB - 1) / EPB;              // 49 binning blocks
    int L = NBUK * nblk;                         // hist entries
    int ntile = (L + 1023) / 1024;               // scan tiles
    int nbuk_eff = (n2 + 127) >> 7;              // 782 non-empty buckets
    int ntiles16 = (n + 15) >> 4;                // 3125 proj tiles

    // workspace (32-bit words):
    // xw1[32n] xw2[32n] (bf16) s1 d1 s2 d2 [n each] wf[16384]
    // hist[L] hscan[L+1] part[1024] offs[n2+1] csr[e2] staging[e2]
    unsigned short* xw1 = (unsigned short*)d_ws;
    unsigned short* xw2 = xw1 + (size_t)n * DOUT;
    float* s1  = (float*)(xw2 + (size_t)n * DOUT);
    float* d1  = s1 + n;
    float* s2  = d1 + n;
    float* d2  = s2 + n;
    unsigned short* wf = (unsigned short*)(d2 + n);   // 32768 ushorts = 16384 words
    int* hist  = (int*)(wf + 32768);
    int* hscan = hist + (size_t)L;
    int* part  = hscan + (size_t)L + 1;
    int* offs  = part + 1024;
    int* csr   = offs + (size_t)n2 + 1;
    unsigned* staging = (unsigned*)(csr + (size_t)e2);

    wfrag_kernel<<<1, 64, 0, stream>>>(W1, W2, wf);
    proj_kernel<<<(ntiles16 + 3) / 4, 256, 0, stream>>>(x, wf, as1, ad1, as2, ad2,
                                                        xw1, xw2, s1, d1, s2, d2, n);

    binhist_kernel<<<nblk, 256, 0, stream>>>(src, dst, hist, e, n, nblk);
    scan_part_kernel<<<ntile, 256, 0, stream>>>(hist, part, L);
    scan_mid_kernel<<<1, 1024, 0, stream>>>(part, ntile, hscan, L, e2);
    scan_apply_kernel<<<ntile, 256, 0, stream>>>(hist, part, hscan, L);
    binscatter_kernel<<<nblk, 256, 0, stream>>>(src, dst, hscan, staging, e, n, nblk);
    buildcsr_kernel<<<nbuk_eff, 256, 0, stream>>>(hscan, staging, csr, offs, n2, e2, nblk);

    long long gthreads = (long long)n * 64;
    int gblocks = (int)((gthreads + 255) / 256);
    gather_kernel<<<gblocks, 256, 0, stream>>>(offs, csr, s1, d1, s2, d2,
                                               xw1, xw2, b1, b2, out, n);
}

// Round 10
// 121.791 us; speedup vs baseline: 2.8460x; 1.3772x over previous
//
#include <hip/hip_runtime.h>

#define DIN 128
#define DOUT 64
#define NEG_SLOPE 0.2f
#define ALPHA 0.5f
#define NBUK 1024   // coarse buckets: bucket = seg >> 7, covers 2n = 100000 segments
#define EPB  2048   // edges per block in binning passes (391 blocks)

typedef __attribute__((ext_vector_type(8))) short bf16x8;
typedef __attribute__((ext_vector_type(4))) float f32x4;

__device__ __forceinline__ float lrelu(float x) { return x > 0.0f ? x : NEG_SLOPE * x; }

__device__ __forceinline__ unsigned short f2bf(float f) {
    unsigned u = __float_as_uint(f);
    unsigned r = (u + 0x7fffu + ((u >> 16) & 1u)) >> 16;
    return (unsigned short)r;
}
__device__ __forceinline__ float bf2f(unsigned short h) {
    return __uint_as_float((unsigned)h << 16);
}
__device__ __forceinline__ float readlane_f(float v, int l) {
    return __int_as_float(__builtin_amdgcn_readlane(__float_as_int(v), l));
}

// ---------------- wfrag: bake W1,W2 into MFMA B-fragment order, split hi/lo.
// One block per (mat,kk,t) combo: 32 blocks x 64 lanes.
// slot k-map (shared by A and B): k = kk*32 + (lane>>4)*8 + j, col = t*16 + (lane&15)
// layout: wf[ ((mat*2+hl)*16 + kk*4 + t) * 512 + lane*8 + j ]
__global__ __launch_bounds__(64) void wfrag_kernel(
    const float* __restrict__ W1, const float* __restrict__ W2,
    unsigned short* __restrict__ wf)
{
    int combo = blockIdx.x;          // [0,32)
    int mat = combo >> 4;
    int kk = (combo >> 2) & 3;
    int t = combo & 3;
    int l = threadIdx.x;
    int g = l >> 4, c = l & 15;
    const float* W = mat ? W2 : W1;
    #pragma unroll
    for (int j = 0; j < 8; ++j) {
        float w = W[(kk * 32 + g * 8 + j) * DOUT + t * 16 + c];
        unsigned short hi = f2bf(w);
        unsigned short lo = f2bf(w - bf2f(hi));
        wf[(size_t)(((mat * 2 + 0) * 16 + kk * 4 + t) * 512) + l * 8 + j] = hi;
        wf[(size_t)(((mat * 2 + 1) * 16 + kk * 4 + t) * 512) + l * 8 + j] = lo;
    }
}

// ---------------- proj via MFMA: one wave per 16-node tile, no LDS.
// xw = x@W via (xhi+xlo)(Whi+Wlo) ~ hi*hi + lo*hi + hi*lo  (f32 accum).
// C/D layout: col = lane&15, row = (lane>>4)*4 + reg  [m89 verified].
__global__ __launch_bounds__(256) void proj_kernel(
    const float* __restrict__ x, const unsigned short* __restrict__ wf,
    const float* __restrict__ as1, const float* __restrict__ ad1,
    const float* __restrict__ as2, const float* __restrict__ ad2,
    unsigned short* __restrict__ xw1, unsigned short* __restrict__ xw2,
    float* __restrict__ s1, float* __restrict__ d1,
    float* __restrict__ s2, float* __restrict__ d2, int n)
{
    int ntiles = (n + 15) >> 4;
    int tile = blockIdx.x * 4 + (threadIdx.x >> 6);
    if (tile >= ntiles) return;
    int l = threadIdx.x & 63;
    int g = l >> 4, c = l & 15;

    int arow = tile * 16 + c;
    if (arow >= n) arow = n - 1;   // clamp: stores are guarded

    // A fragments (x rows), split hi/lo
    bf16x8 ahi[4], alo[4];
    const float* xr = x + (size_t)arow * DIN + g * 8;
    #pragma unroll
    for (int kk = 0; kk < 4; ++kk) {
        float4 v0 = *(const float4*)(xr + kk * 32);
        float4 v1 = *(const float4*)(xr + kk * 32 + 4);
        float xv[8] = {v0.x, v0.y, v0.z, v0.w, v1.x, v1.y, v1.z, v1.w};
        #pragma unroll
        for (int j = 0; j < 8; ++j) {
            unsigned short hi = f2bf(xv[j]);
            unsigned short lo = f2bf(xv[j] - bf2f(hi));
            ahi[kk][j] = (short)hi;
            alo[kk][j] = (short)lo;
        }
    }

    float vs1[4] = {0, 0, 0, 0}, vd1[4] = {0, 0, 0, 0};
    float vs2[4] = {0, 0, 0, 0}, vd2[4] = {0, 0, 0, 0};
    const bf16x8* wfv = (const bf16x8*)wf;   // [(mat2hl)*16 + kk*4+t]*64 + lane

    #pragma unroll
    for (int t = 0; t < 4; ++t) {
        f32x4 C1 = {0.f, 0.f, 0.f, 0.f}, C2 = {0.f, 0.f, 0.f, 0.f};
        #pragma unroll
        for (int kk = 0; kk < 4; ++kk) {
            bf16x8 bh1 = wfv[(size_t)((0 * 16 + kk * 4 + t) * 64) + l];
            bf16x8 bl1 = wfv[(size_t)((1 * 16 + kk * 4 + t) * 64) + l];
            bf16x8 bh2 = wfv[(size_t)((2 * 16 + kk * 4 + t) * 64) + l];
            bf16x8 bl2 = wfv[(size_t)((3 * 16 + kk * 4 + t) * 64) + l];
            C1 = __builtin_amdgcn_mfma_f32_16x16x32_bf16(ahi[kk], bh1, C1, 0, 0, 0);
            C1 = __builtin_amdgcn_mfma_f32_16x16x32_bf16(alo[kk], bh1, C1, 0, 0, 0);
            C1 = __builtin_amdgcn_mfma_f32_16x16x32_bf16(ahi[kk], bl1, C1, 0, 0, 0);
            C2 = __builtin_amdgcn_mfma_f32_16x16x32_bf16(ahi[kk], bh2, C2, 0, 0, 0);
            C2 = __builtin_amdgcn_mfma_f32_16x16x32_bf16(alo[kk], bh2, C2, 0, 0, 0);
            C2 = __builtin_amdgcn_mfma_f32_16x16x32_bf16(ahi[kk], bl2, C2, 0, 0, 0);
        }
        float a1v = as1[t * 16 + c], a2v = ad1[t * 16 + c];
        float a3v = as2[t * 16 + c], a4v = ad2[t * 16 + c];
        #pragma unroll
        for (int r = 0; r < 4; ++r) {
            vs1[r] = fmaf(C1[r], a1v, vs1[r]);
            vd1[r] = fmaf(C1[r], a2v, vd1[r]);
            vs2[r] = fmaf(C2[r], a3v, vs2[r]);
            vd2[r] = fmaf(C2[r], a4v, vd2[r]);
        }
        #pragma unroll
        for (int r = 0; r < 4; ++r) {
            int node = tile * 16 + g * 4 + r;
            if (node < n) {
                xw1[(size_t)node * DOUT + t * 16 + c] = f2bf(C1[r]);
                xw2[(size_t)node * DOUT + t * 16 + c] = f2bf(C2[r]);
            }
        }
    }
    // reduce scores across the 16 lanes of each row-group
    #pragma unroll
    for (int off = 1; off < 16; off <<= 1) {
        #pragma unroll
        for (int r = 0; r < 4; ++r) {
            vs1[r] += __shfl_xor(vs1[r], off);
            vd1[r] += __shfl_xor(vd1[r], off);
            vs2[r] += __shfl_xor(vs2[r], off);
            vd2[r] += __shfl_xor(vd2[r], off);
        }
    }
    if (c == 0) {
        #pragma unroll
        for (int r = 0; r < 4; ++r) {
            int node = tile * 16 + g * 4 + r;
            if (node < n) {
                s1[node] = vs1[r]; d1[node] = vd1[r];
                s2[node] = vs2[r]; d2[node] = vd2[r];
            }
        }
    }
}

// ---------------- pass A1: per-block bucket histogram (no global atomics)
__global__ __launch_bounds__(256) void binhist_kernel(
    const int* __restrict__ src, const int* __restrict__ dst,
    int* __restrict__ hist, int e, int n, int nblk)
{
    __shared__ int cnt[NBUK];
    int tid = threadIdx.x, blk = blockIdx.x;
    for (int b = tid; b < NBUK; b += 256) cnt[b] = 0;
    __syncthreads();
    int base = blk * EPB;
    for (int k = 0; k < EPB / 256; ++k) {
        int t = base + k * 256 + tid;
        if (t < e) {
            int s = src[t], d = dst[t];
            atomicAdd(&cnt[d >> 7], 1);
            atomicAdd(&cnt[(n + s) >> 7], 1);
        }
    }
    __syncthreads();
    for (int b = tid; b < NBUK; b += 256)
        hist[(size_t)b * nblk + blk] = cnt[b];
}

// ---------------- scan chain
__global__ __launch_bounds__(256) void scan_part_kernel(
    const int* __restrict__ deg, int* __restrict__ part, int n2)
{
    __shared__ int sm[256];
    int b = blockIdx.x, t = threadIdx.x;
    int base = b * 1024 + t * 4;
    int s = 0;
    #pragma unroll
    for (int k = 0; k < 4; ++k) { int i = base + k; if (i < n2) s += deg[i]; }
    sm[t] = s; __syncthreads();
    for (int o = 128; o; o >>= 1) { if (t < o) sm[t] += sm[t + o]; __syncthreads(); }
    if (t == 0) part[b] = sm[0];
}

__global__ __launch_bounds__(1024) void scan_mid_kernel(
    int* __restrict__ part, int nb, int* __restrict__ offs, int n2, int total)
{
    __shared__ int sm[1024];
    int t = threadIdx.x;
    int v = (t < nb) ? part[t] : 0;
    sm[t] = v; __syncthreads();
    for (int o = 1; o < 1024; o <<= 1) {
        int u = (t >= o) ? sm[t - o] : 0;
        __syncthreads();
        sm[t] += u;
        __syncthreads();
    }
    if (t < nb) part[t] = sm[t] - v;
    if (t == 0) offs[n2] = total;
}

__global__ __launch_bounds__(256) void scan_apply_kernel(
    const int* __restrict__ deg, const int* __restrict__ part,
    int* __restrict__ offs, int n2)
{
    __shared__ int sm[256];
    int b = blockIdx.x, t = threadIdx.x;
    int base = b * 1024 + t * 4;
    int d[4]; int s = 0;
    #pragma unroll
    for (int k = 0; k < 4; ++k) { int i = base + k; d[k] = (i < n2) ? deg[i] : 0; s += d[k]; }
    sm[t] = s; __syncthreads();
    for (int o = 1; o < 256; o <<= 1) {
        int u = (t >= o) ? sm[t - o] : 0;
        __syncthreads();
        sm[t] += u;
        __syncthreads();
    }
    int run = part[b] + sm[t] - s;
    #pragma unroll
    for (int k = 0; k < 4; ++k) {
        int i = base + k;
        if (i < n2) { offs[i] = run; run += d[k]; }
    }
}

// ---------------- pass A3: bin edges into per-(block,bucket) private chunks.
__global__ __launch_bounds__(256) void binscatter_kernel(
    const int* __restrict__ src, const int* __restrict__ dst,
    const int* __restrict__ hscan, unsigned* __restrict__ staging,
    int e, int n, int nblk)
{
    __shared__ int cur[NBUK];
    int tid = threadIdx.x, blk = blockIdx.x;
    for (int b = tid; b < NBUK; b += 256)
        cur[b] = hscan[(size_t)b * nblk + blk];
    __syncthreads();
    int base = blk * EPB;
    for (int k = 0; k < EPB / 256; ++k) {
        int t = base + k * 256 + tid;
        if (t < e) {
            int s = src[t], d = dst[t];
            int pF = atomicAdd(&cur[d >> 7], 1);
            staging[pF] = ((unsigned)(d & 127) << 16) | (unsigned)s;
            int segR = n + s;
            int pR = atomicAdd(&cur[segR >> 7], 1);
            staging[pR] = ((unsigned)(segR & 127) << 16) | (unsigned)d;
        }
    }
}

// ---------------- pass B: one block per bucket -> offs + csr
__global__ __launch_bounds__(256) void buildcsr_kernel(
    const int* __restrict__ hscan, const unsigned* __restrict__ staging,
    int* __restrict__ csr, int* __restrict__ offs,
    int n2, int e2, int nblk)
{
    __shared__ int segcnt[128];
    __shared__ int segoff[128];
    int b = blockIdx.x, tid = threadIdx.x;
    int lo = hscan[(size_t)b * nblk];
    int hi = hscan[(size_t)(b + 1) * nblk];
    if (tid < 128) segcnt[tid] = 0;
    __syncthreads();
    for (int idx = lo + tid; idx < hi; idx += 256)
        atomicAdd(&segcnt[staging[idx] >> 16], 1);
    __syncthreads();
    if (tid < 64) {
        int a = segcnt[2 * tid], c = segcnt[2 * tid + 1];
        int pair = a + c;
        int inc = pair;
        #pragma unroll
        for (int off = 1; off < 64; off <<= 1) {
            int u = __shfl_up(inc, off);
            if (tid >= off) inc += u;
        }
        int excl = inc - pair;
        segoff[2 * tid] = excl;
        segoff[2 * tid + 1] = excl + a;
    }
    __syncthreads();
    if (tid < 128) {
        int seg = (b << 7) + tid;
        if (seg < n2) offs[seg] = lo + segoff[tid];
        segcnt[tid] = segoff[tid];
    }
    if (b == gridDim.x - 1 && tid == 0) offs[n2] = e2;
    __syncthreads();
    for (int idx = lo + tid; idx < hi; idx += 256) {
        unsigned st = staging[idx];
        int pos = atomicAdd(&segcnt[st >> 16], 1);
        csr[lo + pos] = (int)(st & 0xFFFFu);
    }
}

// ---------------- gather: ONE wave per node, both directions fused.
// 4 independent accumulator chains per direction = 8 loads in flight.
__global__ __launch_bounds__(256) void gather_kernel(
    const int* __restrict__ offs, const int* __restrict__ csr,
    const float* __restrict__ s1, const float* __restrict__ d1,
    const float* __restrict__ s2, const float* __restrict__ d2,
    const unsigned short* __restrict__ xw1, const unsigned short* __restrict__ xw2,
    const float* __restrict__ b1, const float* __restrict__ b2,
    float* __restrict__ out, int n)
{
    int i = (blockIdx.x * 256 + threadIdx.x) >> 6;
    int lane = threadIdx.x & 63;
    if (i >= n) return;

    float d1i = d1[i], d2i = d2[i];
    int cF = offs[i],     endF = offs[i + 1];
    int cR = offs[n + i], endR = offs[n + i + 1];

    float mF = lrelu(s1[i] + d1i), lF = 1.0f;
    float mR = lrelu(s2[i] + d2i), lR = 1.0f;
    float aF0 = bf2f(xw1[(size_t)i * DOUT + lane]), aF1 = 0.f, aF2 = 0.f, aF3 = 0.f;
    float aR0 = bf2f(xw2[(size_t)i * DOUT + lane]), aR1 = 0.f, aR2 = 0.f, aR3 = 0.f;

    while (cF < endF || cR < endR) {
        int cntF = endF - cF; cntF = cntF < 0 ? 0 : (cntF > 64 ? 64 : cntF);
        int cntR = endR - cR; cntR = cntR < 0 ? 0 : (cntR > 64 ? 64 : cntR);

        int jF = 0, jR = 0;
        float scF = -1e30f, scR = -1e30f;
        if (lane < cntF) { jF = csr[cF + lane]; scF = lrelu(s1[jF] + d1i); }
        if (lane < cntR) { jR = csr[cR + lane]; scR = lrelu(s2[jR] + d2i); }

        float cmF = scF, cmR = scR;
        #pragma unroll
        for (int off = 32; off; off >>= 1) {
            cmF = fmaxf(cmF, __shfl_xor(cmF, off));
            cmR = fmaxf(cmR, __shfl_xor(cmR, off));
        }
        float mnF = fmaxf(mF, cmF), mnR = fmaxf(mR, cmR);
        float sclF = __expf(mF - mnF), sclR = __expf(mR - mnR);  // ==1.0 when m>=cm
        float pF = __expf(scF - mnF), pR = __expf(scR - mnR);    // 0 for idle lanes
        float psF = pF, psR = pR;
        #pragma unroll
        for (int off = 32; off; off >>= 1) {
            psF += __shfl_xor(psF, off);
            psR += __shfl_xor(psR, off);
        }
        lF = fmaf(lF, sclF, psF);
        lR = fmaf(lR, sclR, psR);
        aF0 *= sclF; aF1 *= sclF; aF2 *= sclF; aF3 *= sclF;
        aR0 *= sclR; aR1 *= sclR; aR2 *= sclR; aR3 *= sclR;
        mF = mnF; mR = mnR;

        int tmax = cntF > cntR ? cntF : cntR;
        int t = 0;
        for (; t + 4 <= tmax; t += 4) {
            float pF0 = readlane_f(pF, t),     pF1 = readlane_f(pF, t + 1);
            float pF2 = readlane_f(pF, t + 2), pF3 = readlane_f(pF, t + 3);
            int   jF0 = __builtin_amdgcn_readlane(jF, t);
            int   jF1 = __builtin_amdgcn_readlane(jF, t + 1);
            int   jF2 = __builtin_amdgcn_readlane(jF, t + 2);
            int   jF3 = __builtin_amdgcn_readlane(jF, t + 3);
            float pR0 = readlane_f(pR, t),     pR1 = readlane_f(pR, t + 1);
            float pR2 = readlane_f(pR, t + 2), pR3 = readlane_f(pR, t + 3);
            int   jR0 = __builtin_amdgcn_readlane(jR, t);
            int   jR1 = __builtin_amdgcn_readlane(jR, t + 1);
            int   jR2 = __builtin_amdgcn_readlane(jR, t + 2);
            int   jR3 = __builtin_amdgcn_readlane(jR, t + 3);
            aF0 = fmaf(pF0, bf2f(xw1[(size_t)jF0 * DOUT + lane]), aF0);
            aF1 = fmaf(pF1, bf2f(xw1[(size_t)jF1 * DOUT + lane]), aF1);
            aF2 = fmaf(pF2, bf2f(xw1[(size_t)jF2 * DOUT + lane]), aF2);
            aF3 = fmaf(pF3, bf2f(xw1[(size_t)jF3 * DOUT + lane]), aF3);
            aR0 = fmaf(pR0, bf2f(xw2[(size_t)jR0 * DOUT + lane]), aR0);
            aR1 = fmaf(pR1, bf2f(xw2[(size_t)jR1 * DOUT + lane]), aR1);
            aR2 = fmaf(pR2, bf2f(xw2[(size_t)jR2 * DOUT + lane]), aR2);
            aR3 = fmaf(pR3, bf2f(xw2[(size_t)jR3 * DOUT + lane]), aR3);
        }
        for (; t < tmax; ++t) {
            float pF0 = readlane_f(pF, t);
            int   jF0 = __builtin_amdgcn_readlane(jF, t);
            float pR0 = readlane_f(pR, t);
            int   jR0 = __builtin_amdgcn_readlane(jR, t);
            aF0 = fmaf(pF0, bf2f(xw1[(size_t)jF0 * DOUT + lane]), aF0);
            aR0 = fmaf(pR0, bf2f(xw2[(size_t)jR0 * DOUT + lane]), aR0);
        }
        cF += cntF;
        cR += cntR;
    }

    float resF = ((aF0 + aF1) + (aF2 + aF3)) / (lF + 1e-16f);
    float resR = ((aR0 + aR1) + (aR2 + aR3)) / (lR + 1e-16f);
    out[(size_t)i * DOUT + lane] =
        (1.0f - ALPHA) * (resF + b1[lane]) + ALPHA * (resR + b2[lane]);
}

extern "C" void kernel_launch(void* const* d_in, const int* in_sizes, int n_in,
                              void* d_out, int out_size, void* d_ws, size_t ws_size,
                              hipStream_t stream) {
    const float* x   = (const float*)d_in[0];
    const int*   ei  = (const int*)d_in[1];
    const float* W1  = (const float*)d_in[2];
    const float* as1 = (const float*)d_in[3];
    const float* ad1 = (const float*)d_in[4];
    const float* b1  = (const float*)d_in[5];
    const float* W2  = (const float*)d_in[6];
    const float* as2 = (const float*)d_in[7];
    const float* ad2 = (const float*)d_in[8];
    const float* b2  = (const float*)d_in[9];
    float* out = (float*)d_out;

    int n = in_sizes[0] / DIN;   // 50000  (< 65536 for 16-bit staging pack)
    int e = in_sizes[1] / 2;     // 800000
    const int* src = ei;
    const int* dst = ei + e;
    int n2 = 2 * n;
    int e2 = 2 * e;
    int nblk = (e + EPB - 1) / EPB;              // 391 binning blocks
    int L = NBUK * nblk;                         // hist entries (~400K)
    int ntile = (L + 1023) / 1024;               // scan tiles (~392, <=1024)
    int nbuk_eff = (n2 + 127) >> 7;              // 782 non-empty buckets
    int ntiles16 = (n + 15) >> 4;                // 3125 proj tiles

    // workspace (32-bit words):
    // xw1[32n] xw2[32n] (bf16) s1 d1 s2 d2 [n each] wf[16384]
    // hist[L] hscan[L+1] part[1024] offs[n2+1] csr[e2] staging[e2]
    unsigned short* xw1 = (unsigned short*)d_ws;
    unsigned short* xw2 = xw1 + (size_t)n * DOUT;
    float* s1  = (float*)(xw2 + (size_t)n * DOUT);
    float* d1  = s1 + n;
    float* s2  = d1 + n;
    float* d2  = s2 + n;
    unsigned short* wf = (unsigned short*)(d2 + n);   // 32768 ushorts = 16384 words
    int* hist  = (int*)(wf + 32768);
    int* hscan = hist + (size_t)L;
    int* part  = hscan + (size_t)L + 1;
    int* offs  = part + 1024;
    int* csr   = offs + (size_t)n2 + 1;
    unsigned* staging = (unsigned*)(csr + (size_t)e2);

    wfrag_kernel<<<32, 64, 0, stream>>>(W1, W2, wf);
    proj_kernel<<<(ntiles16 + 3) / 4, 256, 0, stream>>>(x, wf, as1, ad1, as2, ad2,
                                                        xw1, xw2, s1, d1, s2, d2, n);

    binhist_kernel<<<nblk, 256, 0, stream>>>(src, dst, hist, e, n, nblk);
    scan_part_kernel<<<ntile, 256, 0, stream>>>(hist, part, L);
    scan_mid_kernel<<<1, 1024, 0, stream>>>(part, ntile, hscan, L, e2);
    scan_apply_kernel<<<ntile, 256, 0, stream>>>(hist, part, hscan, L);
    binscatter_kernel<<<nblk, 256, 0, stream>>>(src, dst, hscan, staging, e, n, nblk);
    buildcsr_kernel<<<nbuk_eff, 256, 0, stream>>>(hscan, staging, csr, offs, n2, e2, nblk);

    long long gthreads = (long long)n * 64;
    int gblocks = (int)((gthreads + 255) / 256);
    gather_kernel<<<gblocks, 256, 0, stream>>>(offs, csr, s1, d1, s2, d2,
                                               xw1, xw2, b1, b2, out, n);
}